// Round 18
// baseline (470.014 us; speedup 1.0000x reference)
//
#include <hip/hip_runtime.h>

typedef __bf16 bf16x8 __attribute__((ext_vector_type(8)));
typedef __bf16 bf16x4 __attribute__((ext_vector_type(4)));
typedef float f32x4 __attribute__((ext_vector_type(4)));

#define MFMA(a,b,c) __builtin_amdgcn_mfma_f32_16x16x32_bf16(a, b, c, 0, 0, 0)

__device__ __forceinline__ float gelu_f(float t) {
    float t2 = t * t;
    float m = t * __builtin_fmaf(-0.07135481627f, t2, -1.5957691216f); // -2z
    float e = __expf(m);
    return t * __builtin_amdgcn_rcpf(1.0f + e);
}

// ---------------- kernel 2 (defined first; R17-measured): LN2 + MLP + residual ----------------
#define LDU 104
#define LDC2 104

__global__ __launch_bounds__(384, 4) void mlp_kernel(
    float* __restrict__ xio, const float* __restrict__ g2v, const float* __restrict__ b2v,
    const float* __restrict__ bm1, const float* __restrict__ bm2,
    const __bf16* __restrict__ ws)
{
    const __bf16* w1t = ws + 36864;
    const __bf16* w2t = ws + 73728;

    __shared__ __align__(16) __bf16 u_lds[64 * LDU];     // 13312 B
    __shared__ __align__(16) __bf16 hid[64 * LDC2];      // 13312 B -> total 26624 B

    const int tid = threadIdx.x;
    const int wv = tid >> 6, lane = tid & 63;     // wv in [0,6)
    const int c = lane & 15, g = lane >> 4;

    const int tok = tid >> 2, cseg = (tid & 3) * 24;   // valid for tid<256
    const long gaddr = ((long)blockIdx.x * 64 + tok) * 96 + cseg;

    const f32x4 fzero = {0.f, 0.f, 0.f, 0.f};

    // ---- LN2 -> u_lds (threads 0..255) ----
    if (tid < 256) {
        float xr[24];
        #pragma unroll
        for (int j = 0; j < 6; ++j) {
            float4 v = *reinterpret_cast<const float4*>(xio + gaddr + j * 4);
            xr[j*4+0] = v.x; xr[j*4+1] = v.y; xr[j*4+2] = v.z; xr[j*4+3] = v.w;
        }
        float s = 0.f;
        #pragma unroll
        for (int j = 0; j < 24; ++j) s += xr[j];
        s += __shfl_xor(s, 1); s += __shfl_xor(s, 2);
        float mu = s * (1.0f / 96.0f);
        float vs = 0.f;
        #pragma unroll
        for (int j = 0; j < 24; ++j) { float d = xr[j] - mu; vs += d * d; }
        vs += __shfl_xor(vs, 1); vs += __shfl_xor(vs, 2);
        float rstd = rsqrtf(vs * (1.0f / 96.0f) + 1e-5f);
        #pragma unroll
        for (int j = 0; j < 6; ++j) {
            f32x4 gv = *reinterpret_cast<const f32x4*>(g2v + cseg + j * 4);
            f32x4 bv = *reinterpret_cast<const f32x4*>(b2v + cseg + j * 4);
            bf16x4 o;
            #pragma unroll
            for (int r = 0; r < 4; ++r) o[r] = (__bf16)((xr[j*4+r] - mu) * rstd * gv[r] + bv[r]);
            *reinterpret_cast<bf16x4*>(&u_lds[tok * LDU + cseg + j*4]) = o;
        }
    }
    __syncthreads();  // bar: u ready

    // ---- MLP: 4 chunks of 96 hidden; wave wv owns hid-tile wv and out-tile wv ----
    f32x4 accB[4];
    #pragma unroll
    for (int tt = 0; tt < 4; ++tt) accB[tt] = fzero;

    #pragma unroll
    for (int ch = 0; ch < 4; ++ch) {
        f32x4 accA[4];
        #pragma unroll
        for (int tt = 0; tt < 4; ++tt) accA[tt] = fzero;
        #pragma unroll
        for (int kc = 0; kc < 3; ++kc) {
            bf16x8 aW = *reinterpret_cast<const bf16x8*>(&w1t[((ch*6 + wv)*16 + c) * 96 + kc*32 + g*8]);
            #pragma unroll
            for (int tt = 0; tt < 4; ++tt) {
                bf16x8 bU = *reinterpret_cast<const bf16x8*>(&u_lds[(tt*16 + c) * LDU + kc*32 + g*8]);
                accA[tt] = MFMA(aW, bU, accA[tt]);
            }
        }
        {
            f32x4 bb = *reinterpret_cast<const f32x4*>(&bm1[(ch*6 + wv)*16 + 4*g]);
            #pragma unroll
            for (int tt = 0; tt < 4; ++tt) {
                bf16x4 o;
                #pragma unroll
                for (int r = 0; r < 4; ++r) o[r] = (__bf16)gelu_f(accA[tt][r] + bb[r]);
                *reinterpret_cast<bf16x4*>(&hid[(tt*16 + c) * LDC2 + wv*16 + 4*g]) = o;
            }
        }
        __syncthreads();  // hid ready

        #pragma unroll
        for (int kc = 0; kc < 3; ++kc) {
            bf16x8 aW2 = *reinterpret_cast<const bf16x8*>(&w2t[(wv*16 + c) * 384 + ch*96 + kc*32 + g*8]);
            #pragma unroll
            for (int tt = 0; tt < 4; ++tt) {
                bf16x8 bHd = *reinterpret_cast<const bf16x8*>(&hid[(tt*16 + c) * LDC2 + kc*32 + g*8]);
                accB[tt] = MFMA(aW2, bHd, accB[tt]);
            }
        }
        if (ch < 3) __syncthreads();  // protect hid overwrite by next chunk
    }

    // ---- epilogue -> u_lds (u is dead) ----
    {
        f32x4 bb = *reinterpret_cast<const f32x4*>(&bm2[wv*16 + 4*g]);
        #pragma unroll
        for (int tt = 0; tt < 4; ++tt) {
            bf16x4 o;
            #pragma unroll
            for (int r = 0; r < 4; ++r) o[r] = (__bf16)(accB[tt][r] + bb[r]);
            *reinterpret_cast<bf16x4*>(&u_lds[(tt*16 + c) * LDU + wv*16 + 4*g]) = o;
        }
    }
    __syncthreads();  // cross-wave epilogue exchange

    // ---- residual ----
    if (tid < 256) {
        #pragma unroll
        for (int j = 0; j < 6; ++j) {
            float4 xv = *reinterpret_cast<const float4*>(xio + gaddr + j * 4);
            bf16x4 mo = *reinterpret_cast<const bf16x4*>(&u_lds[tok * LDU + cseg + j*4]);
            float4 v;
            v.x = xv.x + (float)mo[0];
            v.y = xv.y + (float)mo[1];
            v.z = xv.z + (float)mo[2];
            v.w = xv.w + (float)mo[3];
            *reinterpret_cast<float4*>(xio + gaddr + j * 4) = v;
        }
    }
}

// ---------------- kernel 0: weight prep (transpose + bf16, fold qk scale) ----------------
__global__ void prep_weights(const float* __restrict__ wq, const float* __restrict__ wkv,
                             const float* __restrict__ wp, const float* __restrict__ w1,
                             const float* __restrict__ w2, __bf16* __restrict__ ws) {
    int i = blockIdx.x * 256 + threadIdx.x;
    const float scale = 0.17677669529663687f; // 1/sqrt(32)
    if (i < 9216) {
        int n = i / 96, k = i % 96;
        ws[i] = (__bf16)(wq[k * 96 + n] * scale);
    } else if (i < 27648) {
        int j = i - 9216; int n = j / 96, k = j % 96;
        ws[i] = (__bf16)(wkv[k * 192 + n]);
    } else if (i < 36864) {
        int j = i - 27648; int n = j / 96, k = j % 96;
        ws[i] = (__bf16)(wp[k * 96 + n]);
    } else if (i < 73728) {
        int j = i - 36864; int n = j / 96, k = j % 96;
        ws[i] = (__bf16)(w1[k * 384 + n]);
    } else if (i < 110592) {
        int j = i - 73728; int n = j / 384, k = j % 384;
        ws[i] = (__bf16)(w2[k * 96 + n]);
    }
}

// ---------------- kernel 1: attn (R2 structure; P in dead LDS, swizzled vt; 52.2 KB) ----------------
#define LDH 104

__global__ __launch_bounds__(256, 3) void attn_kernel(
    const float* __restrict__ x, const float* __restrict__ g1v, const float* __restrict__ b1v,
    const float* __restrict__ bq, const float* __restrict__ bkv, const float* __restrict__ bp,
    const __bf16* __restrict__ ws, float* __restrict__ xmid)
{
    const __bf16* wqt  = ws;
    const __bf16* wkvt = ws + 9216;
    const __bf16* wpt  = ws + 27648;

    __shared__ __align__(16) __bf16 h_lds[64 * LDH];   // h -> (P scratch) -> attn_out
    __shared__ __align__(16) __bf16 q_lds[64 * LDH];   // q -> (P scratch h2) -> proj out
    __shared__ __align__(16) __bf16 k_lds[64 * LDH];
    __shared__ __align__(16) __bf16 vt_lds[96 * 64];   // v transposed [vcol][tok], XOR-swizzled rows

    const int tid = threadIdx.x;
    const int wv = tid >> 6, lane = tid & 63;
    const int c = lane & 15, g = lane >> 4;
    const int mp = wv >> 1, ng = wv & 1;

    const int wid = blockIdx.x;
    const int wdI = wid / 576, rem = wid % 576, whI = rem / 24, wwI = rem % 24;
    const int tok = tid >> 2, cseg = (tid & 3) * 24;
    const int dz = tok >> 4, hy = (tok >> 2) & 3, wx = tok & 3;
    const long gbase = (((long)(wdI * 4 + dz) * 96 + (whI * 4 + hy)) * 96 + (wwI * 4 + wx)) * 96 + cseg;

    // ---- load x window to regs, LN1 -> h_lds (bf16) ----
    float xr[24];
    #pragma unroll
    for (int j = 0; j < 6; ++j) {
        float4 v = *reinterpret_cast<const float4*>(x + gbase + j * 4);
        xr[j*4+0] = v.x; xr[j*4+1] = v.y; xr[j*4+2] = v.z; xr[j*4+3] = v.w;
    }
    float s = 0.f;
    #pragma unroll
    for (int j = 0; j < 24; ++j) s += xr[j];
    s += __shfl_xor(s, 1); s += __shfl_xor(s, 2);
    float mu = s * (1.0f / 96.0f);
    float vs = 0.f;
    #pragma unroll
    for (int j = 0; j < 24; ++j) { float d = xr[j] - mu; vs += d * d; }
    vs += __shfl_xor(vs, 1); vs += __shfl_xor(vs, 2);
    float rstd = rsqrtf(vs * (1.0f / 96.0f) + 1e-5f);
    #pragma unroll
    for (int j = 0; j < 6; ++j) {
        float4 gv = *reinterpret_cast<const float4*>(g1v + cseg + j * 4);
        float4 bv = *reinterpret_cast<const float4*>(b1v + cseg + j * 4);
        h_lds[tok * LDH + cseg + j*4+0] = (__bf16)((xr[j*4+0] - mu) * rstd * gv.x + bv.x);
        h_lds[tok * LDH + cseg + j*4+1] = (__bf16)((xr[j*4+1] - mu) * rstd * gv.y + bv.y);
        h_lds[tok * LDH + cseg + j*4+2] = (__bf16)((xr[j*4+2] - mu) * rstd * gv.z + bv.z);
        h_lds[tok * LDH + cseg + j*4+3] = (__bf16)((xr[j*4+3] - mu) * rstd * gv.w + bv.w);
    }
    __syncthreads();  // bar1

    // ---- GEMM1: q = h @ wqt (+ bq*scale) ----
    {
        f32x4 acc[2][3];
        #pragma unroll
        for (int mi = 0; mi < 2; ++mi)
            #pragma unroll
            for (int nl = 0; nl < 3; ++nl) acc[mi][nl] = (f32x4){0.f, 0.f, 0.f, 0.f};
        #pragma unroll
        for (int kc = 0; kc < 3; ++kc) {
            bf16x8 a[2];
            #pragma unroll
            for (int mi = 0; mi < 2; ++mi)
                a[mi] = *reinterpret_cast<const bf16x8*>(&h_lds[((mp*2+mi)*16 + c) * LDH + kc*32 + g*8]);
            #pragma unroll
            for (int nl = 0; nl < 3; ++nl) {
                int nt = ng * 3 + nl;
                bf16x8 b = *reinterpret_cast<const bf16x8*>(&wqt[(nt*16 + c) * 96 + kc*32 + g*8]);
                #pragma unroll
                for (int mi = 0; mi < 2; ++mi)
                    acc[mi][nl] = MFMA(a[mi], b, acc[mi][nl]);
            }
        }
        #pragma unroll
        for (int nl = 0; nl < 3; ++nl) {
            int n = (ng * 3 + nl) * 16 + c;
            float bias = bq[n] * 0.17677669529663687f;
            #pragma unroll
            for (int mi = 0; mi < 2; ++mi)
                #pragma unroll
                for (int r = 0; r < 4; ++r)
                    q_lds[((mp*2+mi)*16 + g*4 + r) * LDH + n] = (__bf16)(acc[mi][nl][r] + bias);
        }
    }

    // ---- GEMM2: kv = h @ wkvt (+bkv) ----
    {
        f32x4 acc[4][3];
        #pragma unroll
        for (int m = 0; m < 4; ++m)
            #pragma unroll
            for (int nl = 0; nl < 3; ++nl) acc[m][nl] = (f32x4){0.f, 0.f, 0.f, 0.f};
        #pragma unroll
        for (int kc = 0; kc < 3; ++kc) {
            bf16x8 a[4];
            #pragma unroll
            for (int m = 0; m < 4; ++m)
                a[m] = *reinterpret_cast<const bf16x8*>(&h_lds[(m*16 + c) * LDH + kc*32 + g*8]);
            #pragma unroll
            for (int nl = 0; nl < 3; ++nl) {
                int nt = wv * 3 + nl;
                bf16x8 b = *reinterpret_cast<const bf16x8*>(&wkvt[(nt*16 + c) * 96 + kc*32 + g*8]);
                #pragma unroll
                for (int m = 0; m < 4; ++m)
                    acc[m][nl] = MFMA(a[m], b, acc[m][nl]);
            }
        }
        #pragma unroll
        for (int nl = 0; nl < 3; ++nl) {
            int n = (wv * 3 + nl) * 16 + c;
            float bias = bkv[n];
            if (wv < 2) {  // k rows
                #pragma unroll
                for (int m = 0; m < 4; ++m)
                    #pragma unroll
                    for (int r = 0; r < 4; ++r)
                        k_lds[(m*16 + g*4 + r) * LDH + n] = (__bf16)(acc[m][nl][r] + bias);
            } else {       // v transposed, swizzled: row nv, byte (32m+8g) ^ ((nv&7)<<4)
                int nv = n - 96;
                #pragma unroll
                for (int m = 0; m < 4; ++m) {
                    bf16x4 pk;
                    pk.x = (__bf16)(acc[m][nl][0] + bias);
                    pk.y = (__bf16)(acc[m][nl][1] + bias);
                    pk.z = (__bf16)(acc[m][nl][2] + bias);
                    pk.w = (__bf16)(acc[m][nl][3] + bias);
                    *reinterpret_cast<bf16x4*>((char*)vt_lds + nv * 128 + ((32*m + 8*g) ^ ((nv & 7) << 4))) = pk;
                }
            }
        }
    }
    __syncthreads();  // bar2: q, k, vt ready; h_lds now dead (reused as P scratch)

    // ---- per head: QK^T + in-register softmax + PV; P in dead LDS columns ----
    #pragma unroll
    for (int h = 0; h < 3; ++h) {
        // P scratch: h0 -> h_lds cols 0-63; h1 -> h_lds cols 32-95; h2 -> q_lds cols 0-63
        __bf16* Pb = (h == 0) ? (h_lds + (wv*16) * LDH)
                   : (h == 1) ? (h_lds + (wv*16) * LDH + 32)
                              : (q_lds + (wv*16) * LDH);
        f32x4 sacc[4];
        #pragma unroll
        for (int nt = 0; nt < 4; ++nt) sacc[nt] = (f32x4){0.f, 0.f, 0.f, 0.f};
        bf16x8 a = *reinterpret_cast<const bf16x8*>(&q_lds[(wv*16 + c) * LDH + h*32 + g*8]);
        #pragma unroll
        for (int nt = 0; nt < 4; ++nt) {
            bf16x8 b = *reinterpret_cast<const bf16x8*>(&k_lds[(nt*16 + c) * LDH + h*32 + g*8]);
            sacc[nt] = MFMA(a, b, sacc[nt]);
        }
        float mx[4];
        #pragma unroll
        for (int r = 0; r < 4; ++r) {
            float m0 = fmaxf(fmaxf(sacc[0][r], sacc[1][r]), fmaxf(sacc[2][r], sacc[3][r]));
            m0 = fmaxf(m0, __shfl_xor(m0, 1));
            m0 = fmaxf(m0, __shfl_xor(m0, 2));
            m0 = fmaxf(m0, __shfl_xor(m0, 4));
            m0 = fmaxf(m0, __shfl_xor(m0, 8));
            mx[r] = m0;
        }
        float p[4][4];
        #pragma unroll
        for (int nt = 0; nt < 4; ++nt)
            #pragma unroll
            for (int r = 0; r < 4; ++r)
                p[nt][r] = __expf(sacc[nt][r] - mx[r]);
        float rsinv[4];
        #pragma unroll
        for (int r = 0; r < 4; ++r) {
            float s0 = p[0][r] + p[1][r] + p[2][r] + p[3][r];
            s0 += __shfl_xor(s0, 1); s0 += __shfl_xor(s0, 2);
            s0 += __shfl_xor(s0, 4); s0 += __shfl_xor(s0, 8);
            rsinv[r] = __builtin_amdgcn_rcpf(s0);
        }
        #pragma unroll
        for (int nt = 0; nt < 4; ++nt)
            #pragma unroll
            for (int r = 0; r < 4; ++r)
                Pb[(g*4 + r) * LDH + nt*16 + c] = (__bf16)p[nt][r];

        f32x4 oacc[2];
        oacc[0] = (f32x4){0.f, 0.f, 0.f, 0.f};
        oacc[1] = (f32x4){0.f, 0.f, 0.f, 0.f};
        #pragma unroll
        for (int kc = 0; kc < 2; ++kc) {
            bf16x8 pa = *reinterpret_cast<const bf16x8*>(&Pb[c * LDH + kc*32 + g*8]);
            #pragma unroll
            for (int n2 = 0; n2 < 2; ++n2) {
                int vr = h*32 + n2*16 + c;
                bf16x8 b = *reinterpret_cast<const bf16x8*>(
                    (const char*)vt_lds + vr * 128 + ((64*kc + 16*g) ^ ((vr & 7) << 4)));
                oacc[n2] = MFMA(pa, b, oacc[n2]);
            }
        }
        #pragma unroll
        for (int n2 = 0; n2 < 2; ++n2)
            #pragma unroll
            for (int r = 0; r < 4; ++r)
                h_lds[(wv*16 + g*4 + r) * LDH + h*32 + n2*16 + c] = (__bf16)(oacc[n2][r] * rsinv[r]);
    }
    __syncthreads();  // bar3: attn_out complete

    // ---- proj: out = attnout @ wpt + bp -> q_lds ----
    {
        f32x4 acc[2][3];
        #pragma unroll
        for (int mi = 0; mi < 2; ++mi)
            #pragma unroll
            for (int nl = 0; nl < 3; ++nl) acc[mi][nl] = (f32x4){0.f, 0.f, 0.f, 0.f};
        #pragma unroll
        for (int kc = 0; kc < 3; ++kc) {
            bf16x8 a[2];
            #pragma unroll
            for (int mi = 0; mi < 2; ++mi)
                a[mi] = *reinterpret_cast<const bf16x8*>(&h_lds[((mp*2+mi)*16 + c) * LDH + kc*32 + g*8]);
            #pragma unroll
            for (int nl = 0; nl < 3; ++nl) {
                int nt = ng * 3 + nl;
                bf16x8 b = *reinterpret_cast<const bf16x8*>(&wpt[(nt*16 + c) * 96 + kc*32 + g*8]);
                #pragma unroll
                for (int mi = 0; mi < 2; ++mi)
                    acc[mi][nl] = MFMA(a[mi], b, acc[mi][nl]);
            }
        }
        __syncthreads();
        #pragma unroll
        for (int nl = 0; nl < 3; ++nl) {
            int n = (ng * 3 + nl) * 16 + c;
            float bias = bp[n];
            #pragma unroll
            for (int mi = 0; mi < 2; ++mi)
                #pragma unroll
                for (int r = 0; r < 4; ++r)
                    q_lds[((mp*2+mi)*16 + g*4 + r) * LDH + n] = (__bf16)(acc[mi][nl][r] + bias);
        }
    }
    __syncthreads();

    // ---- residual: xmid = x + attn_out ----
    #pragma unroll
    for (int j = 0; j < 6; ++j) {
        float4 v;
        v.x = xr[j*4+0] + (float)q_lds[tok * LDH + cseg + j*4+0];
        v.y = xr[j*4+1] + (float)q_lds[tok * LDH + cseg + j*4+1];
        v.z = xr[j*4+2] + (float)q_lds[tok * LDH + cseg + j*4+2];
        v.w = xr[j*4+3] + (float)q_lds[tok * LDH + cseg + j*4+3];
        *reinterpret_cast<float4*>(xmid + gbase + j * 4) = v;
    }
}

extern "C" void kernel_launch(void* const* d_in, const int* in_sizes, int n_in,
                              void* d_out, int out_size, void* d_ws, size_t ws_size,
                              hipStream_t stream) {
    (void)in_sizes; (void)n_in; (void)out_size; (void)ws_size;
    const float* x   = (const float*)d_in[0];
    const float* g1  = (const float*)d_in[1];
    const float* b1  = (const float*)d_in[2];
    const float* wq  = (const float*)d_in[3];
    const float* bq  = (const float*)d_in[4];
    const float* wkv = (const float*)d_in[5];
    const float* bkv = (const float*)d_in[6];
    const float* wp  = (const float*)d_in[7];
    const float* bp  = (const float*)d_in[8];
    const float* g2  = (const float*)d_in[9];
    const float* b2  = (const float*)d_in[10];
    const float* w1  = (const float*)d_in[11];
    const float* bm1 = (const float*)d_in[12];
    const float* w2  = (const float*)d_in[13];
    const float* bm2 = (const float*)d_in[14];
    float* out = (float*)d_out;
    __bf16* ws = (__bf16*)d_ws;

    prep_weights<<<432, 256, 0, stream>>>(wq, wkv, wp, w1, w2, ws);
    attn_kernel<<<9216, 256, 0, stream>>>(x, g1, b1, bq, bkv, bp, ws, out);
    mlp_kernel<<<9216, 384, 0, stream>>>(out, g2, b2, bm1, bm2, ws);
}

// Round 19
// 419.381 us; speedup vs baseline: 1.1207x; 1.1207x over previous
//
#include <hip/hip_runtime.h>

typedef __bf16 bf16x8 __attribute__((ext_vector_type(8)));
typedef __bf16 bf16x4 __attribute__((ext_vector_type(4)));
typedef float f32x4 __attribute__((ext_vector_type(4)));

#define MFMA(a,b,c) __builtin_amdgcn_mfma_f32_16x16x32_bf16(a, b, c, 0, 0, 0)

__device__ __forceinline__ float gelu_f(float t) {
    float t2 = t * t;
    float m = t * __builtin_fmaf(-0.07135481627f, t2, -1.5957691216f); // -2z
    float e = __expf(m);
    return t * __builtin_amdgcn_rcpf(1.0f + e);
}

// ---------------- kernel 2 (defined first): LN2 + MLP + residual ----------------
// MidT = type of the intermediate xmid stream (float: in-place fp32; __bf16: read bf16, write fp32 out)
#define LDU 104
#define LDC2 104

template<typename MidT>
__global__ __launch_bounds__(384, 4) void mlp_kernel(
    const MidT* __restrict__ xin, float* __restrict__ out,
    const float* __restrict__ g2v, const float* __restrict__ b2v,
    const float* __restrict__ bm1, const float* __restrict__ bm2,
    const __bf16* __restrict__ ws)
{
    const __bf16* w1t = ws + 36864;
    const __bf16* w2t = ws + 73728;

    __shared__ __align__(16) __bf16 u_lds[64 * LDU];     // 13312 B
    __shared__ __align__(16) __bf16 hid[64 * LDC2];      // 13312 B -> total 26624 B

    const int tid = threadIdx.x;
    const int wv = tid >> 6, lane = tid & 63;     // wv in [0,6)
    const int c = lane & 15, g = lane >> 4;

    const int tok = tid >> 2, cseg = (tid & 3) * 24;   // valid for tid<256
    const long gaddr = ((long)blockIdx.x * 64 + tok) * 96 + cseg;

    const f32x4 fzero = {0.f, 0.f, 0.f, 0.f};

    // ---- LN2 -> u_lds (threads 0..255) ----
    if (tid < 256) {
        float xr[24];
        if constexpr (sizeof(MidT) == 4) {
            #pragma unroll
            for (int j = 0; j < 6; ++j) {
                float4 v = *reinterpret_cast<const float4*>((const float*)xin + gaddr + j * 4);
                xr[j*4+0] = v.x; xr[j*4+1] = v.y; xr[j*4+2] = v.z; xr[j*4+3] = v.w;
            }
        } else {
            #pragma unroll
            for (int j = 0; j < 3; ++j) {
                bf16x8 v = *reinterpret_cast<const bf16x8*>((const __bf16*)xin + gaddr + j * 8);
                #pragma unroll
                for (int i = 0; i < 8; ++i) xr[j*8+i] = (float)v[i];
            }
        }
        float s = 0.f;
        #pragma unroll
        for (int j = 0; j < 24; ++j) s += xr[j];
        s += __shfl_xor(s, 1); s += __shfl_xor(s, 2);
        float mu = s * (1.0f / 96.0f);
        float vs = 0.f;
        #pragma unroll
        for (int j = 0; j < 24; ++j) { float d = xr[j] - mu; vs += d * d; }
        vs += __shfl_xor(vs, 1); vs += __shfl_xor(vs, 2);
        float rstd = rsqrtf(vs * (1.0f / 96.0f) + 1e-5f);
        #pragma unroll
        for (int j = 0; j < 6; ++j) {
            f32x4 gv = *reinterpret_cast<const f32x4*>(g2v + cseg + j * 4);
            f32x4 bv = *reinterpret_cast<const f32x4*>(b2v + cseg + j * 4);
            bf16x4 o;
            #pragma unroll
            for (int r = 0; r < 4; ++r) o[r] = (__bf16)((xr[j*4+r] - mu) * rstd * gv[r] + bv[r]);
            *reinterpret_cast<bf16x4*>(&u_lds[tok * LDU + cseg + j*4]) = o;
        }
    }
    __syncthreads();  // bar: u ready

    // ---- MLP: 4 chunks of 96 hidden; wave wv owns hid-tile wv and out-tile wv ----
    f32x4 accB[4];
    #pragma unroll
    for (int tt = 0; tt < 4; ++tt) accB[tt] = fzero;

    #pragma unroll
    for (int ch = 0; ch < 4; ++ch) {
        f32x4 accA[4];
        #pragma unroll
        for (int tt = 0; tt < 4; ++tt) accA[tt] = fzero;
        #pragma unroll
        for (int kc = 0; kc < 3; ++kc) {
            bf16x8 aW = *reinterpret_cast<const bf16x8*>(&w1t[((ch*6 + wv)*16 + c) * 96 + kc*32 + g*8]);
            #pragma unroll
            for (int tt = 0; tt < 4; ++tt) {
                bf16x8 bU = *reinterpret_cast<const bf16x8*>(&u_lds[(tt*16 + c) * LDU + kc*32 + g*8]);
                accA[tt] = MFMA(aW, bU, accA[tt]);
            }
        }
        {
            f32x4 bb = *reinterpret_cast<const f32x4*>(&bm1[(ch*6 + wv)*16 + 4*g]);
            #pragma unroll
            for (int tt = 0; tt < 4; ++tt) {
                bf16x4 o;
                #pragma unroll
                for (int r = 0; r < 4; ++r) o[r] = (__bf16)gelu_f(accA[tt][r] + bb[r]);
                *reinterpret_cast<bf16x4*>(&hid[(tt*16 + c) * LDC2 + wv*16 + 4*g]) = o;
            }
        }
        __syncthreads();  // hid ready

        #pragma unroll
        for (int kc = 0; kc < 3; ++kc) {
            bf16x8 aW2 = *reinterpret_cast<const bf16x8*>(&w2t[(wv*16 + c) * 384 + ch*96 + kc*32 + g*8]);
            #pragma unroll
            for (int tt = 0; tt < 4; ++tt) {
                bf16x8 bHd = *reinterpret_cast<const bf16x8*>(&hid[(tt*16 + c) * LDC2 + kc*32 + g*8]);
                accB[tt] = MFMA(aW2, bHd, accB[tt]);
            }
        }
        if (ch < 3) __syncthreads();  // protect hid overwrite by next chunk
    }

    // ---- epilogue -> u_lds (u is dead) ----
    {
        f32x4 bb = *reinterpret_cast<const f32x4*>(&bm2[wv*16 + 4*g]);
        #pragma unroll
        for (int tt = 0; tt < 4; ++tt) {
            bf16x4 o;
            #pragma unroll
            for (int r = 0; r < 4; ++r) o[r] = (__bf16)(accB[tt][r] + bb[r]);
            *reinterpret_cast<bf16x4*>(&u_lds[(tt*16 + c) * LDU + wv*16 + 4*g]) = o;
        }
    }
    __syncthreads();  // cross-wave epilogue exchange

    // ---- residual: out = xmid + mlp ----
    if (tid < 256) {
        #pragma unroll
        for (int j = 0; j < 6; ++j) {
            float xv[4];
            if constexpr (sizeof(MidT) == 4) {
                float4 t = *reinterpret_cast<const float4*>((const float*)xin + gaddr + j * 4);
                xv[0] = t.x; xv[1] = t.y; xv[2] = t.z; xv[3] = t.w;
            } else {
                bf16x4 t = *reinterpret_cast<const bf16x4*>((const __bf16*)xin + gaddr + j * 4);
                #pragma unroll
                for (int r = 0; r < 4; ++r) xv[r] = (float)t[r];
            }
            bf16x4 mo = *reinterpret_cast<const bf16x4*>(&u_lds[tok * LDU + cseg + j*4]);
            float4 v;
            v.x = xv[0] + (float)mo[0];
            v.y = xv[1] + (float)mo[1];
            v.z = xv[2] + (float)mo[2];
            v.w = xv[3] + (float)mo[3];
            *reinterpret_cast<float4*>(out + gaddr + j * 4) = v;
        }
    }
}

// ---------------- kernel 0: weight prep (transpose + bf16, fold qk scale) ----------------
__global__ void prep_weights(const float* __restrict__ wq, const float* __restrict__ wkv,
                             const float* __restrict__ wp, const float* __restrict__ w1,
                             const float* __restrict__ w2, __bf16* __restrict__ ws) {
    int i = blockIdx.x * 256 + threadIdx.x;
    const float scale = 0.17677669529663687f; // 1/sqrt(32)
    if (i < 9216) {
        int n = i / 96, k = i % 96;
        ws[i] = (__bf16)(wq[k * 96 + n] * scale);
    } else if (i < 27648) {
        int j = i - 9216; int n = j / 96, k = j % 96;
        ws[i] = (__bf16)(wkv[k * 192 + n]);
    } else if (i < 36864) {
        int j = i - 27648; int n = j / 96, k = j % 96;
        ws[i] = (__bf16)(wp[k * 96 + n]);
    } else if (i < 73728) {
        int j = i - 36864; int n = j / 96, k = j % 96;
        ws[i] = (__bf16)(w1[k * 384 + n]);
    } else if (i < 110592) {
        int j = i - 73728; int n = j / 384, k = j % 384;
        ws[i] = (__bf16)(w2[k * 96 + n]);
    }
}

// ---------------- kernel 1: attn (R2-measured structure), templated xmid store ----------------
#define LDH 104

template<typename MidT>
__global__ __launch_bounds__(256, 2) void attn_kernel(
    const float* __restrict__ x, const float* __restrict__ g1v, const float* __restrict__ b1v,
    const float* __restrict__ bq, const float* __restrict__ bkv, const float* __restrict__ bp,
    const __bf16* __restrict__ ws, MidT* __restrict__ xmid)
{
    const __bf16* wqt  = ws;
    const __bf16* wkvt = ws + 9216;
    const __bf16* wpt  = ws + 27648;

    __shared__ __align__(16) __bf16 h_lds[64 * LDH];   // h, later attn_out
    __shared__ __align__(16) __bf16 q_lds[64 * LDH];   // q, later proj out
    __shared__ __align__(16) __bf16 k_lds[64 * LDH];
    __shared__ __align__(16) __bf16 vt_lds[96 * 72];   // v transposed [vcol][tok]
    __shared__ __align__(16) __bf16 p_lds[4 * 16 * 72]; // per-wave P scratch

    const int tid = threadIdx.x;
    const int wv = tid >> 6, lane = tid & 63;
    const int c = lane & 15, g = lane >> 4;
    const int mp = wv >> 1, ng = wv & 1;

    const int wid = blockIdx.x;
    const int wdI = wid / 576, rem = wid % 576, whI = rem / 24, wwI = rem % 24;
    const int tok = tid >> 2, cseg = (tid & 3) * 24;
    const int dz = tok >> 4, hy = (tok >> 2) & 3, wx = tok & 3;
    const long gbase = (((long)(wdI * 4 + dz) * 96 + (whI * 4 + hy)) * 96 + (wwI * 4 + wx)) * 96 + cseg;

    // ---- load x window to regs, LN1 -> h_lds (bf16) ----
    float xr[24];
    #pragma unroll
    for (int j = 0; j < 6; ++j) {
        float4 v = *reinterpret_cast<const float4*>(x + gbase + j * 4);
        xr[j*4+0] = v.x; xr[j*4+1] = v.y; xr[j*4+2] = v.z; xr[j*4+3] = v.w;
    }
    float s = 0.f;
    #pragma unroll
    for (int j = 0; j < 24; ++j) s += xr[j];
    s += __shfl_xor(s, 1); s += __shfl_xor(s, 2);
    float mu = s * (1.0f / 96.0f);
    float vs = 0.f;
    #pragma unroll
    for (int j = 0; j < 24; ++j) { float d = xr[j] - mu; vs += d * d; }
    vs += __shfl_xor(vs, 1); vs += __shfl_xor(vs, 2);
    float rstd = rsqrtf(vs * (1.0f / 96.0f) + 1e-5f);
    #pragma unroll
    for (int j = 0; j < 6; ++j) {
        float4 gv = *reinterpret_cast<const float4*>(g1v + cseg + j * 4);
        float4 bv = *reinterpret_cast<const float4*>(b1v + cseg + j * 4);
        h_lds[tok * LDH + cseg + j*4+0] = (__bf16)((xr[j*4+0] - mu) * rstd * gv.x + bv.x);
        h_lds[tok * LDH + cseg + j*4+1] = (__bf16)((xr[j*4+1] - mu) * rstd * gv.y + bv.y);
        h_lds[tok * LDH + cseg + j*4+2] = (__bf16)((xr[j*4+2] - mu) * rstd * gv.z + bv.z);
        h_lds[tok * LDH + cseg + j*4+3] = (__bf16)((xr[j*4+3] - mu) * rstd * gv.w + bv.w);
    }
    __syncthreads();

    // ---- GEMM1: q = h @ wqt (+ bq*scale) ----
    {
        f32x4 acc[2][3];
        #pragma unroll
        for (int mi = 0; mi < 2; ++mi)
            #pragma unroll
            for (int nl = 0; nl < 3; ++nl) acc[mi][nl] = (f32x4){0.f, 0.f, 0.f, 0.f};
        #pragma unroll
        for (int kc = 0; kc < 3; ++kc) {
            bf16x8 a[2];
            #pragma unroll
            for (int mi = 0; mi < 2; ++mi)
                a[mi] = *reinterpret_cast<const bf16x8*>(&h_lds[((mp*2+mi)*16 + c) * LDH + kc*32 + g*8]);
            #pragma unroll
            for (int nl = 0; nl < 3; ++nl) {
                int nt = ng * 3 + nl;
                bf16x8 b = *reinterpret_cast<const bf16x8*>(&wqt[(nt*16 + c) * 96 + kc*32 + g*8]);
                #pragma unroll
                for (int mi = 0; mi < 2; ++mi)
                    acc[mi][nl] = MFMA(a[mi], b, acc[mi][nl]);
            }
        }
        #pragma unroll
        for (int nl = 0; nl < 3; ++nl) {
            int n = (ng * 3 + nl) * 16 + c;
            float bias = bq[n] * 0.17677669529663687f;
            #pragma unroll
            for (int mi = 0; mi < 2; ++mi)
                #pragma unroll
                for (int r = 0; r < 4; ++r)
                    q_lds[((mp*2+mi)*16 + g*4 + r) * LDH + n] = (__bf16)(acc[mi][nl][r] + bias);
        }
    }

    // ---- GEMM2: kv = h @ wkvt (+bkv) ----
    {
        f32x4 acc[4][3];
        #pragma unroll
        for (int m = 0; m < 4; ++m)
            #pragma unroll
            for (int nl = 0; nl < 3; ++nl) acc[m][nl] = (f32x4){0.f, 0.f, 0.f, 0.f};
        #pragma unroll
        for (int kc = 0; kc < 3; ++kc) {
            bf16x8 a[4];
            #pragma unroll
            for (int m = 0; m < 4; ++m)
                a[m] = *reinterpret_cast<const bf16x8*>(&h_lds[(m*16 + c) * LDH + kc*32 + g*8]);
            #pragma unroll
            for (int nl = 0; nl < 3; ++nl) {
                int nt = wv * 3 + nl;
                bf16x8 b = *reinterpret_cast<const bf16x8*>(&wkvt[(nt*16 + c) * 96 + kc*32 + g*8]);
                #pragma unroll
                for (int m = 0; m < 4; ++m)
                    acc[m][nl] = MFMA(a[m], b, acc[m][nl]);
            }
        }
        #pragma unroll
        for (int nl = 0; nl < 3; ++nl) {
            int n = (wv * 3 + nl) * 16 + c;
            float bias = bkv[n];
            if (wv < 2) {  // k rows
                #pragma unroll
                for (int m = 0; m < 4; ++m)
                    #pragma unroll
                    for (int r = 0; r < 4; ++r)
                        k_lds[(m*16 + g*4 + r) * LDH + n] = (__bf16)(acc[m][nl][r] + bias);
            } else {       // v transposed
                int nv = n - 96;
                #pragma unroll
                for (int m = 0; m < 4; ++m) {
                    bf16x4 pk;
                    pk.x = (__bf16)(acc[m][nl][0] + bias);
                    pk.y = (__bf16)(acc[m][nl][1] + bias);
                    pk.z = (__bf16)(acc[m][nl][2] + bias);
                    pk.w = (__bf16)(acc[m][nl][3] + bias);
                    *reinterpret_cast<bf16x4*>(&vt_lds[nv * 72 + m*16 + g*4]) = pk;
                }
            }
        }
    }
    __syncthreads();

    // ---- per head: QK^T + in-register softmax + PV ----
    __bf16* p_w = &p_lds[wv * (16 * 72)];
    #pragma unroll
    for (int h = 0; h < 3; ++h) {
        f32x4 sacc[4];
        #pragma unroll
        for (int nt = 0; nt < 4; ++nt) sacc[nt] = (f32x4){0.f, 0.f, 0.f, 0.f};
        bf16x8 a = *reinterpret_cast<const bf16x8*>(&q_lds[(wv*16 + c) * LDH + h*32 + g*8]);
        #pragma unroll
        for (int nt = 0; nt < 4; ++nt) {
            bf16x8 b = *reinterpret_cast<const bf16x8*>(&k_lds[(nt*16 + c) * LDH + h*32 + g*8]);
            sacc[nt] = MFMA(a, b, sacc[nt]);
        }
        float mx[4];
        #pragma unroll
        for (int r = 0; r < 4; ++r) {
            float m0 = fmaxf(fmaxf(sacc[0][r], sacc[1][r]), fmaxf(sacc[2][r], sacc[3][r]));
            m0 = fmaxf(m0, __shfl_xor(m0, 1));
            m0 = fmaxf(m0, __shfl_xor(m0, 2));
            m0 = fmaxf(m0, __shfl_xor(m0, 4));
            m0 = fmaxf(m0, __shfl_xor(m0, 8));
            mx[r] = m0;
        }
        float p[4][4];
        #pragma unroll
        for (int nt = 0; nt < 4; ++nt)
            #pragma unroll
            for (int r = 0; r < 4; ++r)
                p[nt][r] = __expf(sacc[nt][r] - mx[r]);
        float rsinv[4];
        #pragma unroll
        for (int r = 0; r < 4; ++r) {
            float s0 = p[0][r] + p[1][r] + p[2][r] + p[3][r];
            s0 += __shfl_xor(s0, 1); s0 += __shfl_xor(s0, 2);
            s0 += __shfl_xor(s0, 4); s0 += __shfl_xor(s0, 8);
            rsinv[r] = __builtin_amdgcn_rcpf(s0);
        }
        #pragma unroll
        for (int nt = 0; nt < 4; ++nt)
            #pragma unroll
            for (int r = 0; r < 4; ++r)
                p_w[(g*4 + r) * 72 + nt*16 + c] = (__bf16)p[nt][r];

        f32x4 oacc[2];
        oacc[0] = (f32x4){0.f, 0.f, 0.f, 0.f};
        oacc[1] = (f32x4){0.f, 0.f, 0.f, 0.f};
        #pragma unroll
        for (int kc = 0; kc < 2; ++kc) {
            bf16x8 pa = *reinterpret_cast<const bf16x8*>(&p_w[c * 72 + kc*32 + g*8]);
            #pragma unroll
            for (int n2 = 0; n2 < 2; ++n2) {
                bf16x8 b = *reinterpret_cast<const bf16x8*>(&vt_lds[(h*32 + n2*16 + c) * 72 + kc*32 + g*8]);
                oacc[n2] = MFMA(pa, b, oacc[n2]);
            }
        }
        #pragma unroll
        for (int n2 = 0; n2 < 2; ++n2)
            #pragma unroll
            for (int r = 0; r < 4; ++r)
                h_lds[(wv*16 + g*4 + r) * LDH + h*32 + n2*16 + c] = (__bf16)(oacc[n2][r] * rsinv[r]);
    }
    __syncthreads();

    // ---- proj: out = attnout @ wpt + bp -> q_lds ----
    {
        f32x4 acc[2][3];
        #pragma unroll
        for (int mi = 0; mi < 2; ++mi)
            #pragma unroll
            for (int nl = 0; nl < 3; ++nl) acc[mi][nl] = (f32x4){0.f, 0.f, 0.f, 0.f};
        #pragma unroll
        for (int kc = 0; kc < 3; ++kc) {
            bf16x8 a[2];
            #pragma unroll
            for (int mi = 0; mi < 2; ++mi)
                a[mi] = *reinterpret_cast<const bf16x8*>(&h_lds[((mp*2+mi)*16 + c) * LDH + kc*32 + g*8]);
            #pragma unroll
            for (int nl = 0; nl < 3; ++nl) {
                int nt = ng * 3 + nl;
                bf16x8 b = *reinterpret_cast<const bf16x8*>(&wpt[(nt*16 + c) * 96 + kc*32 + g*8]);
                #pragma unroll
                for (int mi = 0; mi < 2; ++mi)
                    acc[mi][nl] = MFMA(a[mi], b, acc[mi][nl]);
            }
        }
        __syncthreads();
        #pragma unroll
        for (int nl = 0; nl < 3; ++nl) {
            int n = (ng * 3 + nl) * 16 + c;
            float bias = bp[n];
            #pragma unroll
            for (int mi = 0; mi < 2; ++mi)
                #pragma unroll
                for (int r = 0; r < 4; ++r)
                    q_lds[((mp*2+mi)*16 + g*4 + r) * LDH + n] = (__bf16)(acc[mi][nl][r] + bias);
        }
    }
    __syncthreads();

    // ---- residual: xmid = x + attn_out (fp32 or bf16 per MidT) ----
    #pragma unroll
    for (int j = 0; j < 6; ++j) {
        bf16x4 pr = *reinterpret_cast<const bf16x4*>(&q_lds[tok * LDH + cseg + j*4]);
        if constexpr (sizeof(MidT) == 4) {
            float4 v;
            v.x = xr[j*4+0] + (float)pr[0];
            v.y = xr[j*4+1] + (float)pr[1];
            v.z = xr[j*4+2] + (float)pr[2];
            v.w = xr[j*4+3] + (float)pr[3];
            *reinterpret_cast<float4*>((float*)xmid + gbase + j * 4) = v;
        } else {
            bf16x4 o;
            #pragma unroll
            for (int r = 0; r < 4; ++r) o[r] = (__bf16)(xr[j*4+r] + (float)pr[r]);
            *reinterpret_cast<bf16x4*>((__bf16*)xmid + gbase + j * 4) = o;
        }
    }
}

extern "C" void kernel_launch(void* const* d_in, const int* in_sizes, int n_in,
                              void* d_out, int out_size, void* d_ws, size_t ws_size,
                              hipStream_t stream) {
    (void)in_sizes; (void)n_in; (void)out_size;
    const float* x   = (const float*)d_in[0];
    const float* g1  = (const float*)d_in[1];
    const float* b1  = (const float*)d_in[2];
    const float* wq  = (const float*)d_in[3];
    const float* bq  = (const float*)d_in[4];
    const float* wkv = (const float*)d_in[5];
    const float* bkv = (const float*)d_in[6];
    const float* wp  = (const float*)d_in[7];
    const float* bp  = (const float*)d_in[8];
    const float* g2  = (const float*)d_in[9];
    const float* b2  = (const float*)d_in[10];
    const float* w1  = (const float*)d_in[11];
    const float* bm1 = (const float*)d_in[12];
    const float* w2  = (const float*)d_in[13];
    const float* bm2 = (const float*)d_in[14];
    float* out = (float*)d_out;
    __bf16* ws = (__bf16*)d_ws;

    const size_t N_ELEMS = 56623104ULL;              // 64*96*96*96
    const size_t needed  = (110592ULL + N_ELEMS) * 2; // weights + bf16 xmid, bytes

    prep_weights<<<432, 256, 0, stream>>>(wq, wkv, wp, w1, w2, ws);

    if (ws_size >= needed) {
        __bf16* mid = ws + 110592;
        attn_kernel<__bf16><<<9216, 256, 0, stream>>>(x, g1, b1, bq, bkv, bp, ws, mid);
        mlp_kernel<__bf16><<<9216, 384, 0, stream>>>(mid, out, g2, b2, bm1, bm2, ws);
    } else {
        attn_kernel<float><<<9216, 256, 0, stream>>>(x, g1, b1, bq, bkv, bp, ws, out);
        mlp_kernel<float><<<9216, 384, 0, stream>>>(out, out, g2, b2, bm1, bm2, ws);
    }
}